// Round 4
// baseline (478.827 us; speedup 1.0000x reference)
//
#include <hip/hip_runtime.h>
#include <hip/hip_bf16.h>
#include <math.h>

#define DIM 1280
#define NHEADS 16
#define HD 80
#define HDP 96            // head dim padded to 3*32 for MFMA k-steps
#define NSEG 8
#define SEGLEN 1024
#define TOTAL (NSEG*SEGLEN)   // 8192

typedef unsigned short u16;
typedef __attribute__((ext_vector_type(8))) short bf16x8;
typedef __attribute__((ext_vector_type(4))) float f32x4;

// scale * log2(e) folded into Q at QKV-GEMM epilogue
#define QSCALE 0.16129841766598387f   // (1/sqrt(80)) * 1.4426950408889634

__device__ __forceinline__ u16 f2b(float f) {
    union { float f; unsigned int i; } v; v.f = f;
    unsigned int x = v.i;
    unsigned int r = x + 0x7FFFu + ((x >> 16) & 1u);   // RNE
    return (u16)(r >> 16);
}
__device__ __forceinline__ float b2f(u16 u) {
    union { unsigned int i; float f; } v; v.i = ((unsigned int)u) << 16;
    return v.f;
}
__device__ __forceinline__ void gload16(const u16* g, u16* l) {
    __builtin_amdgcn_global_load_lds(
        (const __attribute__((address_space(1))) unsigned int*)g,
        (__attribute__((address_space(3))) unsigned int*)l, 16, 0, 0);
}
__device__ __forceinline__ unsigned int cvt_pk_bf16(float lo, float hi) {
    unsigned int r;
    asm("v_cvt_pk_bf16_f32 %0, %1, %2" : "=v"(r) : "v"(lo), "v"(hi));
    return r;
}

// ---------------------------------------------------------------------------
// fp32 -> bf16 elementwise convert (4 per thread)
// ---------------------------------------------------------------------------
__global__ __launch_bounds__(256) void cvt_f32_bf16(const float* __restrict__ in,
                                                    u16* __restrict__ out, int n4) {
    int i = blockIdx.x * 256 + threadIdx.x;
    if (i >= n4) return;
    float4 a = ((const float4*)in)[i];
    u16 o[4] = { f2b(a.x), f2b(a.y), f2b(a.z), f2b(a.w) };
    *(ulong1*)&out[i*4] = *(ulong1*)o;
}

// ---------------------------------------------------------------------------
// Transpose + convert weights: in [K][N] fp32 -> out [N][K] bf16 (B^T layout)
// ---------------------------------------------------------------------------
__global__ __launch_bounds__(256) void cvtT_w(const float* __restrict__ in,
                                              u16* __restrict__ out, int K, int N) {
    __shared__ float t[32][33];
    const int kb = blockIdx.x * 32, nb = blockIdx.y * 32;
    const int tx = threadIdx.x & 31, ty = threadIdx.x >> 5;
    #pragma unroll
    for (int i = 0; i < 4; ++i) {
        int r = i*8 + ty;
        t[r][tx] = in[(size_t)(kb + r)*N + nb + tx];
    }
    __syncthreads();
    #pragma unroll
    for (int i = 0; i < 4; ++i) {
        int n = i*8 + ty;
        out[(size_t)(nb + n)*K + kb + tx] = f2b(t[tx][n]);
    }
}

// ---------------------------------------------------------------------------
// cos/sin table: cs[s*40+d] = {cos, sin} of rope angle
// ---------------------------------------------------------------------------
__global__ __launch_bounds__(256) void ctab_build(const float* __restrict__ rp,
                                                  float2* __restrict__ cs) {
    int i = blockIdx.x * 256 + threadIdx.x;
    if (i >= TOTAL*40) return;
    float s, c;
    sincosf(rp[i], &s, &c);
    cs[i] = make_float2(c, s);
}

// ---------------------------------------------------------------------------
// 256x256 bf16 MFMA GEMM, 4 compute phases / K-tile, full prefetch at phase 0
// (loads get ~4 phases of MFMA to land; end-of-tile vmcnt(0) ~free).
// 512 thr = 8 waves (2M x 4N), BK=64, dbuf LDS 128KB, XOR chunk swizzle,
// raw barriers + setprio.  MODE 0: fp32 row-major C.  MODE 1: bf16 scatter
// into q ([g][h][l][96], pre-scaled by QSCALE), k ([g][h][l][96]), v (.. [80]).
// ---------------------------------------------------------------------------
template<int MODE>
__global__ __launch_bounds__(512, 2) void gemm8p(
    const u16* __restrict__ A, const u16* __restrict__ BT,
    const float* __restrict__ bias,
    float* __restrict__ Cf, u16* __restrict__ qo, u16* __restrict__ ko,
    u16* __restrict__ vo, int M, int N, int K, int nbx)
{
    __shared__ u16 sA[2][256*64];   // 64KB (dbuf)
    __shared__ u16 sB[2][256*64];   // 64KB

    const int tid = threadIdx.x;
    const int w = tid >> 6, l = tid & 63;
    const int lq = l & 15, lg = l >> 4;
    const int wm = w >> 2, wn = w & 3;

    // XCD-aware bijective block swizzle (gridDim.x % 8 == 0)
    const int nwg = gridDim.x;
    const int q8 = nwg >> 3;
    const int id = blockIdx.x;
    const int id2 = (id & 7) * q8 + (id >> 3);
    const int bx = id2 % nbx, by = id2 / nbx;
    const int brow = by * 256, bcol = bx * 256;

    // staging: LDS linear dest, pre-swizzled global source (chunk ^= row&7)
    const int rlo  = w*8 + (l >> 3);           // row within 64-row stage chunk
    const int srcc = (l & 7) ^ ((l >> 3) & 7); // swizzled source 16B-chunk
    const size_t aBase = (size_t)(brow + rlo)*K + srcc*8;
    const size_t bBase = (size_t)(bcol + rlo)*K + srcc*8;

    // fragment read offsets (u16 units): row*64 + chunk'*8, chunk' = chunk^(lq&7)
    const int cx0 = (0 + lg) ^ (lq & 7);
    const int cx1 = (4 + lg) ^ (lq & 7);

    f32x4 acc[8][4] = {};
    const int NT = K >> 6;   // K/64

    u16* cA = &sA[0][0]; u16* cB = &sB[0][0];
    u16* nA = &sA[1][0]; u16* nB = &sB[1][0];

    // prologue: stage tile 0
    #pragma unroll
    for (int ci = 0; ci < 4; ++ci) {
        gload16(A  + aBase + (size_t)(ci*64)*K, &cA[(ci*512 + w*64)*8]);
        gload16(BT + bBase + (size_t)(ci*64)*K, &cB[(ci*512 + w*64)*8]);
    }
    asm volatile("s_waitcnt vmcnt(0)" ::: "memory");
    __builtin_amdgcn_s_barrier();

    for (int t = 0; t < NT; ++t) {
        const bool pf = (t + 1 < NT);
        const int kb = (t + 1) << 6;
        bf16x8 af[4], bf[4];

        // issue ALL prefetch loads for tile t+1 up front (max flight time)
        if (pf) {
            #pragma unroll
            for (int ci = 0; ci < 4; ++ci) {
                gload16(A  + aBase + (size_t)(ci*64)*K + kb, &nA[(ci*512 + w*64)*8]);
                gload16(BT + bBase + (size_t)(ci*64)*K + kb, &nB[(ci*512 + w*64)*8]);
            }
        }

        // ---- phase 0: s=0, mh=0 --------------------------------------
        #pragma unroll
        for (int n = 0; n < 4; ++n)
            bf[n] = *(const bf16x8*)&cB[(wn*64 + n*16 + lq)*64 + cx0*8];
        #pragma unroll
        for (int mi = 0; mi < 4; ++mi)
            af[mi] = *(const bf16x8*)&cA[(wm*128 + mi*16 + lq)*64 + cx0*8];
        __builtin_amdgcn_s_barrier();
        __builtin_amdgcn_s_setprio(1);
        #pragma unroll
        for (int mi = 0; mi < 4; ++mi)
            #pragma unroll
            for (int n = 0; n < 4; ++n)
                acc[mi][n] = __builtin_amdgcn_mfma_f32_16x16x32_bf16(af[mi], bf[n], acc[mi][n], 0, 0, 0);
        __builtin_amdgcn_s_setprio(0);
        __builtin_amdgcn_s_barrier();

        // ---- phase 1: s=0, mh=1 --------------------------------------
        #pragma unroll
        for (int mi = 0; mi < 4; ++mi)
            af[mi] = *(const bf16x8*)&cA[(wm*128 + 64 + mi*16 + lq)*64 + cx0*8];
        __builtin_amdgcn_s_barrier();
        __builtin_amdgcn_s_setprio(1);
        #pragma unroll
        for (int mi = 0; mi < 4; ++mi)
            #pragma unroll
            for (int n = 0; n < 4; ++n)
                acc[4+mi][n] = __builtin_amdgcn_mfma_f32_16x16x32_bf16(af[mi], bf[n], acc[4+mi][n], 0, 0, 0);
        __builtin_amdgcn_s_setprio(0);
        __builtin_amdgcn_s_barrier();

        // ---- phase 2: s=1, mh=0 --------------------------------------
        #pragma unroll
        for (int n = 0; n < 4; ++n)
            bf[n] = *(const bf16x8*)&cB[(wn*64 + n*16 + lq)*64 + cx1*8];
        #pragma unroll
        for (int mi = 0; mi < 4; ++mi)
            af[mi] = *(const bf16x8*)&cA[(wm*128 + mi*16 + lq)*64 + cx1*8];
        __builtin_amdgcn_s_barrier();
        __builtin_amdgcn_s_setprio(1);
        #pragma unroll
        for (int mi = 0; mi < 4; ++mi)
            #pragma unroll
            for (int n = 0; n < 4; ++n)
                acc[mi][n] = __builtin_amdgcn_mfma_f32_16x16x32_bf16(af[mi], bf[n], acc[mi][n], 0, 0, 0);
        __builtin_amdgcn_s_setprio(0);
        __builtin_amdgcn_s_barrier();

        // ---- phase 3: s=1, mh=1 --------------------------------------
        #pragma unroll
        for (int mi = 0; mi < 4; ++mi)
            af[mi] = *(const bf16x8*)&cA[(wm*128 + 64 + mi*16 + lq)*64 + cx1*8];
        __builtin_amdgcn_s_barrier();
        __builtin_amdgcn_s_setprio(1);
        #pragma unroll
        for (int mi = 0; mi < 4; ++mi)
            #pragma unroll
            for (int n = 0; n < 4; ++n)
                acc[4+mi][n] = __builtin_amdgcn_mfma_f32_16x16x32_bf16(af[mi], bf[n], acc[4+mi][n], 0, 0, 0);
        __builtin_amdgcn_s_setprio(0);
        if (pf) asm volatile("s_waitcnt vmcnt(0)" ::: "memory");
        __builtin_amdgcn_s_barrier();

        u16* tA = cA; cA = nA; nA = tA;
        u16* tB = cB; cB = nB; nB = tB;
    }

    // epilogue
    #pragma unroll
    for (int mf = 0; mf < 8; ++mf) {
        #pragma unroll
        for (int n = 0; n < 4; ++n) {
            const int col = bcol + wn*64 + n*16 + lq;
            const float bv = bias[col];
            #pragma unroll
            for (int r = 0; r < 4; ++r) {
                const int row = brow + wm*128 + mf*16 + lg*4 + r;
                float val = acc[mf][n][r] + bv;
                if (MODE == 0) {
                    Cf[(size_t)row*N + col] = val;
                } else {
                    int part = col / DIM, rem = col - part*DIM;
                    int hh = rem / HD, dd = rem - hh*HD;
                    int g = row >> 10, ll = row & 1023;
                    size_t tok = (size_t)((g*NHEADS + hh)*SEGLEN + ll);
                    if      (part == 0) qo[tok*HDP + dd] = f2b(val * QSCALE);
                    else if (part == 1) ko[tok*HDP + dd] = f2b(val);
                    else                vo[tok*HD  + dd] = f2b(val);
                }
            }
        }
    }
}

// ---------------------------------------------------------------------------
// Vectorized RoPE in-place on bf16 q,k ([g][h][l][96]); zero-fills pads.
// ---------------------------------------------------------------------------
__global__ __launch_bounds__(256) void rope_pad2(u16* __restrict__ qb, u16* __restrict__ kb,
                                                 const float2* __restrict__ cs)
{
    int idx = blockIdx.x * 256 + threadIdx.x;       // 131072 rows
    int l = idx & 1023, h = (idx >> 10) & 15, g = idx >> 14;
    size_t base = ((size_t)((g*NHEADS + h)*SEGLEN + l)) * HDP;
    const float2* c0 = cs + (size_t)(g*SEGLEN + l) * 40;
    #pragma unroll
    for (int p = 0; p < 5; ++p) {
        float cv[8], sv[8];
        #pragma unroll
        for (int j2 = 0; j2 < 4; ++j2) {
            float4 f = ((const float4*)(c0 + p*8))[j2];
            cv[j2*2] = f.x; sv[j2*2] = f.y; cv[j2*2+1] = f.z; sv[j2*2+1] = f.w;
        }
        bf16x8 qlo = *(const bf16x8*)&qb[base + p*8];
        bf16x8 qhi = *(const bf16x8*)&qb[base + 40 + p*8];
        bf16x8 klo = *(const bf16x8*)&kb[base + p*8];
        bf16x8 khi = *(const bf16x8*)&kb[base + 40 + p*8];
        bf16x8 qlo2, qhi2, klo2, khi2;
        #pragma unroll
        for (int j = 0; j < 8; ++j) {
            float a  = b2f((u16)qlo[j]), b  = b2f((u16)qhi[j]);
            qlo2[j] = (short)f2b(a*cv[j]  - b*sv[j]);
            qhi2[j] = (short)f2b(b*cv[j]  + a*sv[j]);
            float ka = b2f((u16)klo[j]), kb2 = b2f((u16)khi[j]);
            klo2[j] = (short)f2b(ka*cv[j] - kb2*sv[j]);
            khi2[j] = (short)f2b(kb2*cv[j] + ka*sv[j]);
        }
        *(bf16x8*)&qb[base + p*8]      = qlo2;
        *(bf16x8*)&qb[base + 40 + p*8] = qhi2;
        *(bf16x8*)&kb[base + p*8]      = klo2;
        *(bf16x8*)&kb[base + 40 + p*8] = khi2;
    }
    bf16x8 z = {};
    *(bf16x8*)&qb[base + 80] = z; *(bf16x8*)&qb[base + 88] = z;
    *(bf16x8*)&kb[base + 80] = z; *(bf16x8*)&kb[base + 88] = z;
}

// ---------------------------------------------------------------------------
// V transpose per head: v [gh][1024][80] -> vt [gh][80][1024]  (bf16)
// ---------------------------------------------------------------------------
__global__ __launch_bounds__(256) void transpose_v(const u16* __restrict__ v,
                                                   u16* __restrict__ vt)
{
    __shared__ u16 sT[64][82];
    const int gh = blockIdx.y;
    const int st = blockIdx.x;
    const u16* src = v  + (size_t)gh*SEGLEN*HD + (size_t)st*64*HD;
    u16*       dst = vt + (size_t)gh*HD*SEGLEN + (size_t)st*64;
    const int tid = threadIdx.x;
    #pragma unroll
    for (int p = 0; p < 20; ++p) {
        int e = p*256 + tid;
        int r = e / 80, c = e - r*80;
        sT[r][c] = src[r*HD + c];
    }
    __syncthreads();
    #pragma unroll
    for (int p = 0; p < 20; ++p) {
        int e = p*256 + tid;
        int dd = e >> 6, s = e & 63;
        dst[(size_t)dd*SEGLEN + s] = sT[s][dd];
    }
}

// ---------------------------------------------------------------------------
// Flash attention, bf16 MFMA, fp32 online softmax in log2 domain.
// Q pre-scaled by scale*log2(e) at QKV epilogue.  sK XOR-chunk-swizzled
// (both-sides involution, global_load_lds-compatible).  T13 defer-max.
// ---------------------------------------------------------------------------
__global__ __launch_bounds__(256) void attn_mfma(
    const u16* __restrict__ qb, const u16* __restrict__ kb,
    const u16* __restrict__ vt, u16* __restrict__ ob)
{
    const int qt = blockIdx.x;
    const int h  = blockIdx.y;
    const int g  = blockIdx.z;

    __shared__ u16 sK[64*HDP];        // 768 16B-chunks, 12 blocks of 64, swizzled
    __shared__ u16 sVT[80][72];
    __shared__ u16 sP[4][16][72];

    const int tid = threadIdx.x;
    const int w = tid >> 6, l = tid & 63;
    const int lq = l & 15, lg = l >> 4;

    const size_t gh = (size_t)(g*NHEADS + h);
    const u16* Qg  = qb + gh*SEGLEN*HDP + (size_t)qt*64*HDP;
    const u16* Kg  = kb + gh*SEGLEN*HDP;
    const u16* VTg = vt + gh*HD*SEGLEN;

    // staging source (pre-swizzled): lane l in block b fetches global chunk
    // b*64 + sig(l), sig(x) = x ^ ((x>>3)&7)  (involution, bits0-2 ^= bits3-5)
    const int sig_l = l ^ ((l >> 3) & 7);
    int srow[3], scc[3];
    #pragma unroll
    for (int i = 0; i < 3; ++i) {
        int gi = (i*4 + w)*64 + sig_l;
        srow[i] = gi / 12;            // 12 chunks per 96-u16 row
        scc[i]  = gi % 12;
    }

    bf16x8 qf[3];
    #pragma unroll
    for (int s = 0; s < 3; ++s)
        qf[s] = *(const bf16x8*)(Qg + (size_t)(w*16 + lq)*HDP + s*32 + lg*8);

    float m = -1e30f, lse = 0.f;
    f32x4 Oc[5] = {};

    for (int kt = 0; kt < 16; ++kt) {
        __syncthreads();
        #pragma unroll
        for (int i = 0; i < 3; ++i)
            gload16(Kg + (size_t)(kt*64 + srow[i])*HDP + scc[i]*8, &sK[(i*4 + w)*512]);
        #pragma unroll
        for (int p = 0; p < 3; ++p) {
            int c = p*256 + tid;
            if (c < 640) {
                int dd = c >> 3, s8 = (c & 7)*8;
                *(bf16x8*)&sVT[dd][s8] =
                    *(const bf16x8*)(VTg + (size_t)dd*SEGLEN + kt*64 + s8);
            }
        }
        __syncthreads();

        // QK^T (swapped): A-frag from swizzled sK
        f32x4 sf[4];
        #pragma unroll
        for (int fi = 0; fi < 4; ++fi) {
            f32x4 c = {0.f, 0.f, 0.f, 0.f};
            #pragma unroll
            for (int s = 0; s < 3; ++s) {
                int flat = (fi*16 + lq)*12 + s*4 + lg;
                int c6 = flat & 63;
                int lc = (flat & ~63) | (c6 ^ ((c6 >> 3) & 7));
                bf16x8 a = *(const bf16x8*)&sK[lc*8];
                c = __builtin_amdgcn_mfma_f32_16x16x32_bf16(a, qf[s], c, 0, 0, 0);
            }
            sf[fi] = c;
        }

        // online softmax (log2 domain; scores already scaled by scale*log2e)
        float sv[4][4];
        float rm = -1e30f;
        #pragma unroll
        for (int fi = 0; fi < 4; ++fi)
            #pragma unroll
            for (int r = 0; r < 4; ++r) {
                float x = sf[fi][r];
                sv[fi][r] = x;
                rm = fmaxf(rm, x);
            }
        rm = fmaxf(rm, __shfl_xor(rm, 16, 64));
        rm = fmaxf(rm, __shfl_xor(rm, 32, 64));

        if (__all(rm <= m + 8.0f)) {
            // defer-max: keep old m, no O-rescale (P bounded by 2^8)
            float psum = 0.f;
            #pragma unroll
            for (int fi = 0; fi < 4; ++fi)
                #pragma unroll
                for (int r = 0; r < 4; ++r) {
                    float p = exp2f(sv[fi][r] - m);
                    sv[fi][r] = p;
                    psum += p;
                }
            psum += __shfl_xor(psum, 16, 64);
            psum += __shfl_xor(psum, 32, 64);
            lse += psum;
        } else {
            float mnew = fmaxf(m, rm);
            float alpha = exp2f(m - mnew);
            float psum = 0.f;
            #pragma unroll
            for (int fi = 0; fi < 4; ++fi)
                #pragma unroll
                for (int r = 0; r < 4; ++r) {
                    float p = exp2f(sv[fi][r] - mnew);
                    sv[fi][r] = p;
                    psum += p;
                }
            psum += __shfl_xor(psum, 16, 64);
            psum += __shfl_xor(psum, 32, 64);
            lse = lse * alpha + psum;
            m = mnew;
            float a0 = __shfl(alpha, lg*4 + 0, 64);
            float a1 = __shfl(alpha, lg*4 + 1, 64);
            float a2 = __shfl(alpha, lg*4 + 2, 64);
            float a3 = __shfl(alpha, lg*4 + 3, 64);
            #pragma unroll
            for (int n = 0; n < 5; ++n) {
                Oc[n][0] *= a0; Oc[n][1] *= a1; Oc[n][2] *= a2; Oc[n][3] *= a3;
            }
        }

        // pack P -> bf16 via v_cvt_pk_bf16_f32
        #pragma unroll
        for (int fi = 0; fi < 4; ++fi) {
            uint2 val;
            val.x = cvt_pk_bf16(sv[fi][0], sv[fi][1]);
            val.y = cvt_pk_bf16(sv[fi][2], sv[fi][3]);
            *(uint2*)&sP[w][lq][fi*16 + lg*4] = val;
        }

        // PV
        #pragma unroll
        for (int ks = 0; ks < 2; ++ks) {
            bf16x8 pa = *(const bf16x8*)&sP[w][lq][ks*32 + lg*8];
            #pragma unroll
            for (int n = 0; n < 5; ++n) {
                bf16x8 vb = *(const bf16x8*)&sVT[n*16 + lq][ks*32 + lg*8];
                Oc[n] = __builtin_amdgcn_mfma_f32_16x16x32_bf16(pa, vb, Oc[n], 0, 0, 0);
            }
        }
    }

    float inv = 1.f / lse;
    float i0 = __shfl(inv, lg*4 + 0, 64);
    float i1 = __shfl(inv, lg*4 + 1, 64);
    float i2 = __shfl(inv, lg*4 + 2, 64);
    float i3 = __shfl(inv, lg*4 + 3, 64);
    const float iv[4] = { i0, i1, i2, i3 };
    #pragma unroll
    for (int n = 0; n < 5; ++n) {
        #pragma unroll
        for (int r = 0; r < 4; ++r) {
            int tok = g*SEGLEN + qt*64 + w*16 + lg*4 + r;
            int col = h*HD + n*16 + lq;
            ob[(size_t)tok*DIM + col] = f2b(Oc[n][r] * iv[r]);
        }
    }
}

// ---------------------------------------------------------------------------
extern "C" void kernel_launch(void* const* d_in, const int* in_sizes, int n_in,
                              void* d_out, int out_size, void* d_ws, size_t ws_size,
                              hipStream_t stream) {
    const float* hs     = (const float*)d_in[0];
    const float* rope   = (const float*)d_in[1];
    const float* qkv_w  = (const float*)d_in[2];
    const float* qkv_b  = (const float*)d_in[3];
    const float* proj_w = (const float*)d_in[4];
    const float* proj_b = (const float*)d_in[5];

    char* ws = (char*)d_ws;
    u16* hsb    = (u16*)(ws);                 // 8192x1280 bf16   (20,971,520 B)
    u16* wqkvt  = (u16*)(ws + 20971520);      // 3840x1280        ( 9,830,400 B)
    u16* wprojt = (u16*)(ws + 30801920);      // 1280x1280        ( 3,276,800 B)
    u16* qpad   = (u16*)(ws + 34078720);      // 128x1024x96      (25,165,824 B)
    u16* kpad   = (u16*)(ws + 59244544);      // 128x1024x96      (25,165,824 B)
    u16* vbuf   = (u16*)(ws + 84410368);      // 128x1024x80      (20,971,520 B)
    u16* vtb    = (u16*)(ws + 105381888);     // 128x80x1024      (20,971,520 B)
    u16* obb    = (u16*)(ws + 126353408);     // 8192x1280        (20,971,520 B)
    // ctab aliases obb: ctab dead (after rope) before obb is written (attn)
    float2* ctab = (float2*)(ws + 126353408); // 8192x40 float2   ( 2,621,440 B)

    // 1. converts + rope table
    cvt_f32_bf16<<<(TOTAL*DIM/4 + 255)/256, 256, 0, stream>>>(hs, hsb, TOTAL*DIM/4);
    cvtT_w<<<dim3(DIM/32, 3*DIM/32), 256, 0, stream>>>(qkv_w, wqkvt, DIM, 3*DIM);
    cvtT_w<<<dim3(DIM/32, DIM/32), 256, 0, stream>>>(proj_w, wprojt, DIM, DIM);
    ctab_build<<<(TOTAL*40 + 255)/256, 256, 0, stream>>>(rope, ctab);

    // 2. QKV GEMM + scatter (Q pre-scaled): grid 15x32 = 480 blocks
    gemm8p<1><<<dim3((3*DIM/256) * (TOTAL/256)), 512, 0, stream>>>(
        hsb, wqkvt, qkv_b, nullptr, qpad, kpad, vbuf, TOTAL, 3*DIM, DIM, 3*DIM/256);

    // 3. RoPE + pad zero-fill (vectorized)
    rope_pad2<<<NSEG*NHEADS*SEGLEN/256, 256, 0, stream>>>(qpad, kpad, ctab);

    // 4. V transpose
    transpose_v<<<dim3(SEGLEN/64, NSEG*NHEADS), 256, 0, stream>>>(vbuf, vtb);

    // 5. flash attention
    attn_mfma<<<dim3(SEGLEN/64, NHEADS, NSEG), 256, 0, stream>>>(qpad, kpad, vtb, obb);

    // 6. output projection
    gemm8p<0><<<dim3((DIM/256) * (TOTAL/256)), 512, 0, stream>>>(
        obb, wprojt, proj_b, (float*)d_out, nullptr, nullptr, nullptr, TOTAL, DIM, DIM, DIM/256);
}

// Round 5
// 433.973 us; speedup vs baseline: 1.1034x; 1.1034x over previous
//
#include <hip/hip_runtime.h>
#include <hip/hip_bf16.h>
#include <math.h>

#define DIM 1280
#define NHEADS 16
#define HD 80
#define HDP 96            // head dim padded to 3*32 for MFMA k-steps
#define NSEG 8
#define SEGLEN 1024
#define TOTAL (NSEG*SEGLEN)   // 8192

typedef unsigned short u16;
typedef __attribute__((ext_vector_type(8))) short bf16x8;
typedef __attribute__((ext_vector_type(4))) float f32x4;

// scale * log2(e) folded into Q at QKV-GEMM epilogue
#define QSCALE 0.16129841766598387f   // (1/sqrt(80)) * 1.4426950408889634

__device__ __forceinline__ u16 f2b(float f) {
    union { float f; unsigned int i; } v; v.f = f;
    unsigned int x = v.i;
    unsigned int r = x + 0x7FFFu + ((x >> 16) & 1u);   // RNE
    return (u16)(r >> 16);
}
__device__ __forceinline__ float b2f(u16 u) {
    union { unsigned int i; float f; } v; v.i = ((unsigned int)u) << 16;
    return v.f;
}
__device__ __forceinline__ void gload16(const u16* g, u16* l) {
    __builtin_amdgcn_global_load_lds(
        (const __attribute__((address_space(1))) unsigned int*)g,
        (__attribute__((address_space(3))) unsigned int*)l, 16, 0, 0);
}
__device__ __forceinline__ unsigned int cvt_pk_bf16(float lo, float hi) {
    unsigned int r;
    asm("v_cvt_pk_bf16_f32 %0, %1, %2" : "=v"(r) : "v"(lo), "v"(hi));
    return r;
}

// ---------------------------------------------------------------------------
// fp32 -> bf16 elementwise convert (4 per thread)
// ---------------------------------------------------------------------------
__global__ __launch_bounds__(256) void cvt_f32_bf16(const float* __restrict__ in,
                                                    u16* __restrict__ out, int n4) {
    int i = blockIdx.x * 256 + threadIdx.x;
    if (i >= n4) return;
    float4 a = ((const float4*)in)[i];
    u16 o[4] = { f2b(a.x), f2b(a.y), f2b(a.z), f2b(a.w) };
    *(ulong1*)&out[i*4] = *(ulong1*)o;
}

// ---------------------------------------------------------------------------
// Transpose + convert weights: in [K][N] fp32 -> out [N][K] bf16 (B^T layout)
// ---------------------------------------------------------------------------
__global__ __launch_bounds__(256) void cvtT_w(const float* __restrict__ in,
                                              u16* __restrict__ out, int K, int N) {
    __shared__ float t[32][33];
    const int kb = blockIdx.x * 32, nb = blockIdx.y * 32;
    const int tx = threadIdx.x & 31, ty = threadIdx.x >> 5;
    #pragma unroll
    for (int i = 0; i < 4; ++i) {
        int r = i*8 + ty;
        t[r][tx] = in[(size_t)(kb + r)*N + nb + tx];
    }
    __syncthreads();
    #pragma unroll
    for (int i = 0; i < 4; ++i) {
        int n = i*8 + ty;
        out[(size_t)(nb + n)*K + kb + tx] = f2b(t[tx][n]);
    }
}

// ---------------------------------------------------------------------------
// cos/sin table: cs[s*40+d] = {cos, sin} of rope angle
// ---------------------------------------------------------------------------
__global__ __launch_bounds__(256) void ctab_build(const float* __restrict__ rp,
                                                  float2* __restrict__ cs) {
    int i = blockIdx.x * 256 + threadIdx.x;
    if (i >= TOTAL*40) return;
    float s, c;
    sincosf(rp[i], &s, &c);
    cs[i] = make_float2(c, s);
}

// ---------------------------------------------------------------------------
// 256x256 bf16 MFMA GEMM, counted-vmcnt 2-tile-deep pipeline (T4), K=1280.
// 512 thr = 8 waves (2M x 4N), BK=64, dbuf LDS 128KB, XOR chunk swizzle on
// stage-source + read-index (both-sides involution), 2 barriers/tile.
// At top of tile t: wait vmcnt(8) -> tile t landed, tile t+1 stays in flight.
// MODE 0: fp32 row-major C.  MODE 1: bf16 scatter into q ([g][h][l][96],
// pre-scaled by QSCALE), k ([g][h][l][96]), v TRANSPOSED ([g*16+h][80][1024]).
// ---------------------------------------------------------------------------
template<int MODE>
__global__ __launch_bounds__(512, 2) void gemm_cv(
    const u16* __restrict__ A, const u16* __restrict__ BT,
    const float* __restrict__ bias,
    float* __restrict__ Cf, u16* __restrict__ qo, u16* __restrict__ ko,
    u16* __restrict__ vo, int M, int N, int nbx)
{
    const int K = 1280;
    const int NT = 20;               // K / 64
    __shared__ u16 sA[2][256*64];    // 64KB (dbuf)
    __shared__ u16 sB[2][256*64];    // 64KB

    const int tid = threadIdx.x;
    const int w = tid >> 6, l = tid & 63;
    const int lq = l & 15, lg = l >> 4;
    const int wm = w >> 2, wn = w & 3;

    // XCD-aware bijective block swizzle (gridDim.x % 8 == 0)
    const int nwg = gridDim.x;
    const int q8 = nwg >> 3;
    const int id = blockIdx.x;
    const int id2 = (id & 7) * q8 + (id >> 3);
    const int bx = id2 % nbx, by = id2 / nbx;
    const int brow = by * 256, bcol = bx * 256;

    // staging: LDS linear dest, pre-swizzled global source (chunk ^= row&7)
    const int rlo  = w*8 + (l >> 3);           // row within 64-row stage chunk
    const int srcc = (l & 7) ^ ((l >> 3) & 7); // swizzled source 16B-chunk
    const size_t aBase = (size_t)(brow + rlo)*K + srcc*8;
    const size_t bBase = (size_t)(bcol + rlo)*K + srcc*8;

    // fragment read offsets (16B chunks): chunk' = chunk ^ (row&7), row&7==lq&7
    const int cx0 = (0 + lg) ^ (lq & 7);
    const int cx1 = (4 + lg) ^ (lq & 7);

    f32x4 acc[8][4] = {};

    u16* cA = &sA[0][0]; u16* cB = &sB[0][0];
    u16* nA = &sA[1][0]; u16* nB = &sB[1][0];

    // prologue: stage tile 0 -> c, tile 1 -> n  (8 loads per thread per tile)
    #pragma unroll
    for (int ci = 0; ci < 4; ++ci) {
        gload16(A  + aBase + (size_t)(ci*64)*K, &cA[(ci*512 + w*64)*8]);
        gload16(BT + bBase + (size_t)(ci*64)*K, &cB[(ci*512 + w*64)*8]);
    }
    #pragma unroll
    for (int ci = 0; ci < 4; ++ci) {
        gload16(A  + aBase + (size_t)(ci*64)*K + 64, &nA[(ci*512 + w*64)*8]);
        gload16(BT + bBase + (size_t)(ci*64)*K + 64, &nB[(ci*512 + w*64)*8]);
    }

    #pragma unroll 2
    for (int t = 0; t < NT; ++t) {
        // counted wait: tile t landed; tile t+1's 8 loads stay in flight
        if (t < NT - 1) asm volatile("s_waitcnt vmcnt(8)" ::: "memory");
        else            asm volatile("s_waitcnt vmcnt(0)" ::: "memory");
        __builtin_amdgcn_s_barrier();

        #pragma unroll
        for (int kh = 0; kh < 2; ++kh) {
            const int cx = kh ? cx1 : cx0;
            bf16x8 bf[4];
            #pragma unroll
            for (int n = 0; n < 4; ++n)
                bf[n] = *(const bf16x8*)&cB[(wn*64 + n*16 + lq)*64 + cx*8];
            #pragma unroll
            for (int mh = 0; mh < 2; ++mh) {
                bf16x8 af[4];
                #pragma unroll
                for (int mi = 0; mi < 4; ++mi)
                    af[mi] = *(const bf16x8*)&cA[(wm*128 + mh*64 + mi*16 + lq)*64 + cx*8];
                __builtin_amdgcn_s_setprio(1);
                #pragma unroll
                for (int mi = 0; mi < 4; ++mi)
                    #pragma unroll
                    for (int n = 0; n < 4; ++n)
                        acc[mh*4 + mi][n] = __builtin_amdgcn_mfma_f32_16x16x32_bf16(
                            af[mi], bf[n], acc[mh*4 + mi][n], 0, 0, 0);
                __builtin_amdgcn_s_setprio(0);
            }
        }
        __builtin_amdgcn_s_barrier();   // all waves done reading c-buffer

        if (t + 2 < NT) {               // stage tile t+2 into the freed buffer
            const size_t kb2 = (size_t)(t + 2) * 64;
            #pragma unroll
            for (int ci = 0; ci < 4; ++ci) {
                gload16(A  + aBase + (size_t)(ci*64)*K + kb2, &cA[(ci*512 + w*64)*8]);
                gload16(BT + bBase + (size_t)(ci*64)*K + kb2, &cB[(ci*512 + w*64)*8]);
            }
        }
        u16* tA = cA; cA = nA; nA = tA;
        u16* tB = cB; cB = nB; nB = tB;
    }

    // epilogue
    #pragma unroll
    for (int mf = 0; mf < 8; ++mf) {
        #pragma unroll
        for (int n = 0; n < 4; ++n) {
            const int col = bcol + wn*64 + n*16 + lq;
            const float bv = bias[col];
            #pragma unroll
            for (int r = 0; r < 4; ++r) {
                const int row = brow + wm*128 + mf*16 + lg*4 + r;
                float val = acc[mf][n][r] + bv;
                if (MODE == 0) {
                    Cf[(size_t)row*N + col] = val;
                } else {
                    int part = col / DIM, rem = col - part*DIM;
                    int hh = rem / HD, dd = rem - hh*HD;
                    int g = row >> 10, ll = row & 1023;
                    size_t tok = (size_t)((g*NHEADS + hh)*SEGLEN + ll);
                    if      (part == 0) qo[tok*HDP + dd] = f2b(val * QSCALE);
                    else if (part == 1) ko[tok*HDP + dd] = f2b(val);
                    else    vo[((size_t)(g*NHEADS + hh)*HD + dd)*SEGLEN + ll] = f2b(val);
                }
            }
        }
    }
}

// ---------------------------------------------------------------------------
// RoPE in-place on bf16 q,k ([g][h][l][96]); 6 tasks per row:
// task 0..4 = one 8-pair rotate group; task 5 = zero pads 80..95.
// ---------------------------------------------------------------------------
__global__ __launch_bounds__(256) void rope_pad3(u16* __restrict__ qb, u16* __restrict__ kb,
                                                 const float2* __restrict__ cs)
{
    int idx = blockIdx.x * 256 + threadIdx.x;   // 131072 * 6
    int row = idx / 6, task = idx - row*6;      // row = (g*16+h)*1024 + l
    size_t base = (size_t)row * HDP;
    if (task == 5) {
        bf16x8 z = {};
        *(bf16x8*)&qb[base + 80] = z; *(bf16x8*)&qb[base + 88] = z;
        *(bf16x8*)&kb[base + 80] = z; *(bf16x8*)&kb[base + 88] = z;
        return;
    }
    const int p = task;
    int l = row & 1023, g = row >> 14;
    const float2* c0 = cs + ((size_t)((g << 10) | l))*40 + p*8;
    float cv[8], sv[8];
    #pragma unroll
    for (int j2 = 0; j2 < 4; ++j2) {
        float4 f = ((const float4*)c0)[j2];
        cv[j2*2] = f.x; sv[j2*2] = f.y; cv[j2*2+1] = f.z; sv[j2*2+1] = f.w;
    }
    bf16x8 qlo = *(const bf16x8*)&qb[base + p*8];
    bf16x8 qhi = *(const bf16x8*)&qb[base + 40 + p*8];
    bf16x8 klo = *(const bf16x8*)&kb[base + p*8];
    bf16x8 khi = *(const bf16x8*)&kb[base + 40 + p*8];
    bf16x8 qlo2, qhi2, klo2, khi2;
    #pragma unroll
    for (int j = 0; j < 8; ++j) {
        float a  = b2f((u16)qlo[j]), b  = b2f((u16)qhi[j]);
        qlo2[j] = (short)f2b(a*cv[j]  - b*sv[j]);
        qhi2[j] = (short)f2b(b*cv[j]  + a*sv[j]);
        float ka = b2f((u16)klo[j]), kb2 = b2f((u16)khi[j]);
        klo2[j] = (short)f2b(ka*cv[j] - kb2*sv[j]);
        khi2[j] = (short)f2b(kb2*cv[j] + ka*sv[j]);
    }
    *(bf16x8*)&qb[base + p*8]      = qlo2;
    *(bf16x8*)&qb[base + 40 + p*8] = qhi2;
    *(bf16x8*)&kb[base + p*8]      = klo2;
    *(bf16x8*)&kb[base + 40 + p*8] = khi2;
}

// ---------------------------------------------------------------------------
// Flash attention, bf16 MFMA, fp32 online softmax in log2 domain.
// QBLK=128: 4 waves, each owns 32 q rows (2 qsets of 16).  KVBLK=64.
// Q pre-scaled by scale*log2(e).  Linear sK staging (R3 layout, uniform banks).
// ---------------------------------------------------------------------------
__device__ __forceinline__ void sm_update(float sv[4][4], float& m, float& lse,
                                          f32x4* Oc, const int lg)
{
    float rm = -1e30f;
    #pragma unroll
    for (int fi = 0; fi < 4; ++fi)
        #pragma unroll
        for (int r = 0; r < 4; ++r) rm = fmaxf(rm, sv[fi][r]);
    rm = fmaxf(rm, __shfl_xor(rm, 16, 64));
    rm = fmaxf(rm, __shfl_xor(rm, 32, 64));

    if (__all(rm <= m + 8.0f)) {
        float psum = 0.f;
        #pragma unroll
        for (int fi = 0; fi < 4; ++fi)
            #pragma unroll
            for (int r = 0; r < 4; ++r) {
                float p = exp2f(sv[fi][r] - m);
                sv[fi][r] = p;
                psum += p;
            }
        psum += __shfl_xor(psum, 16, 64);
        psum += __shfl_xor(psum, 32, 64);
        lse += psum;
    } else {
        float mnew = fmaxf(m, rm);
        float alpha = exp2f(m - mnew);
        float psum = 0.f;
        #pragma unroll
        for (int fi = 0; fi < 4; ++fi)
            #pragma unroll
            for (int r = 0; r < 4; ++r) {
                float p = exp2f(sv[fi][r] - mnew);
                sv[fi][r] = p;
                psum += p;
            }
        psum += __shfl_xor(psum, 16, 64);
        psum += __shfl_xor(psum, 32, 64);
        lse = lse * alpha + psum;
        m = mnew;
        float a0 = __shfl(alpha, lg*4 + 0, 64);
        float a1 = __shfl(alpha, lg*4 + 1, 64);
        float a2 = __shfl(alpha, lg*4 + 2, 64);
        float a3 = __shfl(alpha, lg*4 + 3, 64);
        #pragma unroll
        for (int n = 0; n < 5; ++n) {
            Oc[n][0] *= a0; Oc[n][1] *= a1; Oc[n][2] *= a2; Oc[n][3] *= a3;
        }
    }
}

__global__ __launch_bounds__(256) void attn_mfma(
    const u16* __restrict__ qb, const u16* __restrict__ kb,
    const u16* __restrict__ vt, u16* __restrict__ ob)
{
    const int qt = blockIdx.x;   // 0..7  (128-row q tiles)
    const int h  = blockIdx.y;
    const int g  = blockIdx.z;

    __shared__ u16 sK[64*HDP];        // 12288 B, linear (global_load_lds)
    __shared__ u16 sVT[80][72];       // 11520 B
    __shared__ u16 sP[4][32][72];     // 18432 B (per-wave, 2 qsets)

    const int tid = threadIdx.x;
    const int w = tid >> 6, l = tid & 63;
    const int lq = l & 15, lg = l >> 4;

    const size_t gh = (size_t)(g*NHEADS + h);
    const u16* Qg  = qb + gh*SEGLEN*HDP + (size_t)qt*128*HDP;
    const u16* Kg  = kb + gh*SEGLEN*HDP;
    const u16* VTg = vt + gh*HD*SEGLEN;

    // Q B-fragments: qset qs covers q rows w*32+qs*16 .. +16
    bf16x8 qf[2][3];
    #pragma unroll
    for (int qs = 0; qs < 2; ++qs)
        #pragma unroll
        for (int s = 0; s < 3; ++s)
            qf[qs][s] = *(const bf16x8*)(Qg + (size_t)(w*32 + qs*16 + lq)*HDP + s*32 + lg*8);

    float m0 = -1e30f, lse0 = 0.f, m1 = -1e30f, lse1 = 0.f;
    f32x4 Oc0[5] = {}, Oc1[5] = {};

    for (int kt = 0; kt < 16; ++kt) {
        __syncthreads();
        // stage K tile 64x96 (12KB): 12 chunks of 1KB
        #pragma unroll
        for (int i = 0; i < 3; ++i) {
            int o = (i*4 + w)*1024 + l*16;
            int row = o / 192, cc = (o % 192) >> 1;
            gload16(Kg + (size_t)(kt*64 + row)*HDP + cc, &sK[(i*4 + w)*512]);
        }
        // stage V^T tile 80x64 (reg-staged, padded rows)
        #pragma unroll
        for (int p = 0; p < 3; ++p) {
            int c = p*256 + tid;
            if (c < 640) {
                int dd = c >> 3, s8 = (c & 7)*8;
                *(bf16x8*)&sVT[dd][s8] =
                    *(const bf16x8*)(VTg + (size_t)dd*SEGLEN + kt*64 + s8);
            }
        }
        __syncthreads();

        #pragma unroll
        for (int qs = 0; qs < 2; ++qs) {
            // QK^T (swapped): lane l holds S[k=fi*16+lg*4+r][q=w*32+qs*16+lq]
            float sv[4][4];
            #pragma unroll
            for (int fi = 0; fi < 4; ++fi) {
                f32x4 c = {0.f, 0.f, 0.f, 0.f};
                #pragma unroll
                for (int s = 0; s < 3; ++s) {
                    bf16x8 a = *(const bf16x8*)&sK[(fi*16 + lq)*HDP + s*32 + lg*8];
                    c = __builtin_amdgcn_mfma_f32_16x16x32_bf16(a, qf[qs][s], c, 0, 0, 0);
                }
                #pragma unroll
                for (int r = 0; r < 4; ++r) sv[fi][r] = c[r];
            }

            if (qs == 0) sm_update(sv, m0, lse0, Oc0, lg);
            else         sm_update(sv, m1, lse1, Oc1, lg);

            // pack P -> bf16
            #pragma unroll
            for (int fi = 0; fi < 4; ++fi) {
                uint2 val;
                val.x = cvt_pk_bf16(sv[fi][0], sv[fi][1]);
                val.y = cvt_pk_bf16(sv[fi][2], sv[fi][3]);
                *(uint2*)&sP[w][qs*16 + lq][fi*16 + lg*4] = val;
            }

            // PV
            f32x4* Oc = (qs == 0) ? Oc0 : Oc1;
            #pragma unroll
            for (int ks = 0; ks < 2; ++ks) {
                bf16x8 pa = *(const bf16x8*)&sP[w][qs*16 + lq][ks*32 + lg*8];
                #pragma unroll
                for (int n = 0; n < 5; ++n) {
                    bf16x8 vb = *(const bf16x8*)&sVT[n*16 + lq][ks*32 + lg*8];
                    Oc[n] = __builtin_amdgcn_mfma_f32_16x16x32_bf16(pa, vb, Oc[n], 0, 0, 0);
                }
            }
        }
    }

    #pragma unroll
    for (int qs = 0; qs < 2; ++qs) {
        float lse = (qs == 0) ? lse0 : lse1;
        const f32x4* Oc = (qs == 0) ? Oc0 : Oc1;
        float inv = 1.f / lse;
        float i0 = __shfl(inv, lg*4 + 0, 64);
        float i1 = __shfl(inv, lg*4 + 1, 64);
        float i2 = __shfl(inv, lg*4 + 2, 64);
        float i3 = __shfl(inv, lg*4 + 3, 64);
        const float iv[4] = { i0, i1, i2, i3 };
        #pragma unroll
        for (int n = 0; n < 5; ++n) {
            #pragma unroll
            for (int r = 0; r < 4; ++r) {
                int tok = g*SEGLEN + qt*128 + w*32 + qs*16 + lg*4 + r;
                int col = h*HD + n*16 + lq;
                ob[(size_t)tok*DIM + col] = f2b(Oc[n][r] * iv[r]);
            }
        }
    }
}

// ---------------------------------------------------------------------------
extern "C" void kernel_launch(void* const* d_in, const int* in_sizes, int n_in,
                              void* d_out, int out_size, void* d_ws, size_t ws_size,
                              hipStream_t stream) {
    const float* hs     = (const float*)d_in[0];
    const float* rope   = (const float*)d_in[1];
    const float* qkv_w  = (const float*)d_in[2];
    const float* qkv_b  = (const float*)d_in[3];
    const float* proj_w = (const float*)d_in[4];
    const float* proj_b = (const float*)d_in[5];

    char* ws = (char*)d_ws;
    u16* hsb    = (u16*)(ws);                 // 8192x1280 bf16   (20,971,520 B)
    u16* wqkvt  = (u16*)(ws + 20971520);      // 3840x1280        ( 9,830,400 B)
    u16* wprojt = (u16*)(ws + 30801920);      // 1280x1280        ( 3,276,800 B)
    u16* qpad   = (u16*)(ws + 34078720);      // 128x1024x96      (25,165,824 B)
    u16* kpad   = (u16*)(ws + 59244544);      // 128x1024x96      (25,165,824 B)
    u16* vtb    = (u16*)(ws + 84410368);      // 128x80x1024      (20,971,520 B)
    u16* obb    = (u16*)(ws + 105381888);     // 8192x1280        (20,971,520 B)
    // ctab aliases obb: ctab dead (after rope) before obb is written (attn)
    float2* ctab = (float2*)(ws + 105381888); // 8192x40 float2   ( 2,621,440 B)

    // 1. converts + rope table
    cvt_f32_bf16<<<(TOTAL*DIM/4 + 255)/256, 256, 0, stream>>>(hs, hsb, TOTAL*DIM/4);
    cvtT_w<<<dim3(DIM/32, 3*DIM/32), 256, 0, stream>>>(qkv_w, wqkvt, DIM, 3*DIM);
    cvtT_w<<<dim3(DIM/32, DIM/32), 256, 0, stream>>>(proj_w, wprojt, DIM, DIM);
    ctab_build<<<(TOTAL*40 + 255)/256, 256, 0, stream>>>(rope, ctab);

    // 2. QKV GEMM + scatter (Q pre-scaled, V transposed): 480 blocks
    gemm_cv<1><<<dim3((3*DIM/256) * (TOTAL/256)), 512, 0, stream>>>(
        hsb, wqkvt, qkv_b, nullptr, qpad, kpad, vtb, TOTAL, 3*DIM, 3*DIM/256);

    // 3. RoPE + pad zero-fill (6 tasks/row)
    rope_pad3<<<NSEG*NHEADS*SEGLEN*6/256, 256, 0, stream>>>(qpad, kpad, ctab);

    // 4. flash attention (QBLK=128): 1024 blocks
    attn_mfma<<<dim3(SEGLEN/128, NHEADS, NSEG), 256, 0, stream>>>(qpad, kpad, vtb, obb);

    // 5. output projection: 160 blocks
    gemm_cv<0><<<dim3((DIM/256) * (TOTAL/256)), 512, 0, stream>>>(
        obb, wprojt, proj_b, (float*)d_out, nullptr, nullptr, nullptr, TOTAL, DIM, DIM/256);
}